// Round 3
// baseline (1494.145 us; speedup 1.0000x reference)
//
#include <hip/hip_runtime.h>
#include <stdint.h>

// B=16, T=64, H=1024, D=2048, EMB=512, MAXOUT=1024, VOCAB=32000

typedef __attribute__((ext_vector_type(8))) short bf16x8;
typedef __attribute__((ext_vector_type(4))) float f32x4;

__device__ __forceinline__ uint16_t f2b(float x) {
  uint32_t u = __float_as_uint(x);
  return (uint16_t)((u + 0x7FFFu + ((u >> 16) & 1u)) >> 16);
}
__device__ __forceinline__ float b2f(uint16_t x) {
  return __uint_as_float(((uint32_t)x) << 16);
}

struct us4 { uint16_t a, b, c, d; };

// ---------------- convert f32 -> bf16 (no transpose) ----------------
__global__ void k_cvt_bf16(const float* __restrict__ in, uint16_t* __restrict__ out, int n4) {
  int i = blockIdx.x * 256 + threadIdx.x;
  if (i >= n4) return;
  float4 v = ((const float4*)in)[i];
  us4 o; o.a = f2b(v.x); o.b = f2b(v.y); o.c = f2b(v.z); o.d = f2b(v.w);
  ((us4*)out)[i] = o;
}

// ---------------- transpose f32 [R][C] -> bf16 [C][R] ----------------
__global__ void k_transpose_bf16(const float* __restrict__ in, uint16_t* __restrict__ out,
                                 int R, int C) {
  __shared__ float tile[32][33];
  int c0 = blockIdx.x * 32, r0 = blockIdx.y * 32;
  int tx = threadIdx.x & 31, ty = threadIdx.x >> 5;  // ty 0..7
  #pragma unroll
  for (int i = 0; i < 4; ++i) {
    int r = ty + i * 8;
    tile[r][tx] = in[(size_t)(r0 + r) * C + c0 + tx];
  }
  __syncthreads();
  #pragma unroll
  for (int i = 0; i < 4; ++i) {
    int r = ty + i * 8;
    out[(size_t)(c0 + r) * R + r0 + tx] = f2b(tile[tx][r]);
  }
}

// ---------------- generic bf16 MFMA GEMM: C = A[M][K] * BT[N][K]^T + bias ----------------
// MODE 0: f32 store C[row*ldc+col]
// MODE 1: bf16 store
// MODE 2: f32 store remapped: row=(t*16+b) -> C[(b*64+t)*ldc+col]
template<int MODE>
__global__ __launch_bounds__(256) void k_gemm(
    const uint16_t* __restrict__ A, int lda,
    const uint16_t* __restrict__ BT, int ldb,
    void* __restrict__ C, int ldc, const float* __restrict__ bias,
    int M, int N, int K) {
  __shared__ uint16_t sA[128 * 64];
  __shared__ uint16_t sB[128 * 64];
  const int tid = threadIdx.x;
  const int wave = tid >> 6, lane = tid & 63;
  const int r16 = lane & 15, g = lane >> 4;
  const int wr = wave >> 1, wc = wave & 1;
  const int m0 = blockIdx.y * 128, n0 = blockIdx.x * 128;
  f32x4 acc[4][4] = {};
  for (int k0 = 0; k0 < K; k0 += 64) {
    __syncthreads();
    #pragma unroll
    for (int i = 0; i < 4; ++i) {
      int chunk = wave * 256 + i * 64 + lane;
      int row = chunk >> 3, c8 = chunk & 7;
      int arow = m0 + row; arow = arow < M ? arow : M - 1;
      int brow = n0 + row; brow = brow < N ? brow : N - 1;
      const uint16_t* ga = A + (size_t)arow * lda + k0 + c8 * 8;
      const uint16_t* gb = BT + (size_t)brow * ldb + k0 + c8 * 8;
      uint16_t* la = sA + (size_t)(wave * 256 + i * 64) * 8;
      uint16_t* lb = sB + (size_t)(wave * 256 + i * 64) * 8;
      __builtin_amdgcn_global_load_lds((const __attribute__((address_space(1))) void*)ga,
                                       (__attribute__((address_space(3))) void*)la, 16, 0, 0);
      __builtin_amdgcn_global_load_lds((const __attribute__((address_space(1))) void*)gb,
                                       (__attribute__((address_space(3))) void*)lb, 16, 0, 0);
    }
    __syncthreads();
    #pragma unroll
    for (int kk = 0; kk < 2; ++kk) {
      bf16x8 af[4], bfr[4];
      #pragma unroll
      for (int mi = 0; mi < 4; ++mi)
        af[mi] = *(const bf16x8*)&sA[(wr * 64 + mi * 16 + r16) * 64 + kk * 32 + g * 8];
      #pragma unroll
      for (int ni = 0; ni < 4; ++ni)
        bfr[ni] = *(const bf16x8*)&sB[(wc * 64 + ni * 16 + r16) * 64 + kk * 32 + g * 8];
      #pragma unroll
      for (int mi = 0; mi < 4; ++mi)
        #pragma unroll
        for (int ni = 0; ni < 4; ++ni)
          acc[mi][ni] = __builtin_amdgcn_mfma_f32_16x16x32_bf16(af[mi], bfr[ni], acc[mi][ni], 0, 0, 0);
    }
  }
  #pragma unroll
  for (int mi = 0; mi < 4; ++mi) {
    #pragma unroll
    for (int ni = 0; ni < 4; ++ni) {
      int col = n0 + wc * 64 + ni * 16 + r16;
      if (col >= N) continue;
      float bv = bias ? bias[col] : 0.0f;
      #pragma unroll
      for (int r = 0; r < 4; ++r) {
        int row = m0 + wr * 64 + mi * 16 + 4 * g + r;
        if (row >= M) continue;
        float v = acc[mi][ni][r] + bv;
        if (MODE == 0) {
          ((float*)C)[(size_t)row * ldc + col] = v;
        } else if (MODE == 1) {
          ((uint16_t*)C)[(size_t)row * ldc + col] = f2b(v);
        } else {
          int tstep = row >> 4, bb = row & 15;
          ((float*)C)[(size_t)(bb * 64 + tstep) * ldc + col] = v;
        }
      }
    }
  }
}

// ---------------- maxout: tt[1024][2048] f32 -> t_all[1024][1024] bf16 ----------------
__global__ void k_maxout(const float* __restrict__ tt, uint16_t* __restrict__ tout) {
  int i = blockIdx.x * 256 + threadIdx.x;
  int m = i >> 10, n = i & 1023;
  tout[i] = f2b(fmaxf(tt[(size_t)m * 2048 + n], tt[(size_t)m * 2048 + 1024 + n]));
}

// ---------------- scan state ----------------
struct ScanParams {
  const uint16_t* h_bf;   // [1024][2048] bf16 (rows b*64+t)
  const uint16_t* WsT;    // [64][1024] bf16
  const uint16_t* WhhT;   // [3072][1024] bf16
  const uint16_t* Hih;    // [1024][3072] bf16 (rows b*64+t)
  const float* hemb;      // [1024][64] f32 (rows b*64+t)
  const float* b_s; const float* b_ih; const float* b_hh;
  float* abuf;            // [16][64]
  float* gi;              // [16][3072]
  float* gh;              // [16][3072]
  float* sf0; float* sf1; // [16][1024] f32 state ping-pong
  uint16_t* sb;           // [16][1024] bf16 state
  uint16_t* X;            // [1024][3584] bf16 concat buffer (rows t*16+b)
};

// ---- stepA: (t>0) GRU -> s(t), write X row t-1; alignment a(t). grid 64x256 ----
__global__ __launch_bounds__(256) void k_stepA(ScanParams p, int t) {
  const int bid = blockIdx.x, tid = threadIdx.x;
  __shared__ float s_new[1024];
  const int b = bid >> 2, tc = (bid & 3) << 4;
  if (t > 0) {
    const float* sfr = ((t - 1) & 1) ? p.sf1 : p.sf0;
    float* sfw = (t & 1) ? p.sf1 : p.sf0;
    #pragma unroll
    for (int u = 0; u < 4; ++u) {
      int j = tid + u * 256;
      float ir = p.gi[b * 3072 + j],         hr = p.gh[b * 3072 + j];
      float iz = p.gi[b * 3072 + 1024 + j],  hz = p.gh[b * 3072 + 1024 + j];
      float in_ = p.gi[b * 3072 + 2048 + j], hn = p.gh[b * 3072 + 2048 + j];
      float rr = 1.0f / (1.0f + __expf(-(ir + hr)));
      float zz = 1.0f / (1.0f + __expf(-(iz + hz)));
      float nn = tanhf(in_ + rr * hn);
      float sv = (1.0f - zz) * nn + zz * sfr[b * 1024 + j];
      s_new[j] = sv;
      if ((bid & 3) == 0) {
        sfw[b * 1024 + j] = sv;
        p.sb[b * 1024 + j] = f2b(sv);
        p.X[(size_t)((t - 1) * 16 + b) * 3584 + j] = f2b(sv);
      }
    }
  } else {
    #pragma unroll
    for (int u = 0; u < 4; ++u) {
      int j = tid + u * 256;
      s_new[j] = 0.0f;
      if ((bid & 3) == 0) { p.sf0[b * 1024 + j] = 0.0f; p.sb[b * 1024 + j] = 0; }
    }
  }
  __syncthreads();
  int tp = tid >> 4, kl = tid & 15;
  const uint16_t* wrow = p.WsT + (size_t)(tc + tp) * 1024;
  float av = 0.0f;
  for (int u = 0; u < 64; ++u) { int k = kl + u * 16; av += s_new[k] * b2f(wrow[k]); }
  av += __shfl_xor(av, 8, 16);
  av += __shfl_xor(av, 4, 16);
  av += __shfl_xor(av, 2, 16);
  av += __shfl_xor(av, 1, 16);
  if (kl == 0) {
    int tg = tc + tp;
    p.abuf[b * 64 + tg] = tanhf(av + p.b_s[tg] + p.hemb[(size_t)(b * 64 + t) * 64 + tg]);
  }
}

// ---- final GRU: s(64) -> X row 63*16+b. grid 16x256 ----
__global__ __launch_bounds__(256) void k_stepFinal(ScanParams p) {
  const int b = blockIdx.x, tid = threadIdx.x;
  #pragma unroll
  for (int u = 0; u < 4; ++u) {
    int j = tid + u * 256;
    float ir = p.gi[b * 3072 + j],         hr = p.gh[b * 3072 + j];
    float iz = p.gi[b * 3072 + 1024 + j],  hz = p.gh[b * 3072 + 1024 + j];
    float in_ = p.gi[b * 3072 + 2048 + j], hn = p.gh[b * 3072 + 2048 + j];
    float rr = 1.0f / (1.0f + __expf(-(ir + hr)));
    float zz = 1.0f / (1.0f + __expf(-(iz + hz)));
    float nn = tanhf(in_ + rr * hn);
    float sv = (1.0f - zz) * nn + zz * p.sf1[b * 1024 + j];
    p.X[(size_t)(63 * 16 + b) * 3584 + j] = f2b(sv);
  }
}

__device__ __forceinline__ void softmax64(const float* __restrict__ arow, float* e_lds, int tid) {
  if (tid < 64) {
    float v = arow[tid];
    float m = v;
    #pragma unroll
    for (int mask = 32; mask; mask >>= 1) m = fmaxf(m, __shfl_xor(m, mask));
    float pv = __expf(v - m);
    float s = pv;
    #pragma unroll
    for (int mask = 32; mask; mask >>= 1) s += __shfl_xor(s, mask);
    e_lds[tid] = pv / s;
  }
  __syncthreads();
}

// ---- stepB: gh = s@W_hh + b_hh (MFMA); gi = e@H_ih + b_ih; c -> X. grid 992x256 ----
__global__ __launch_bounds__(256) void k_stepB(ScanParams p, int t) {
  const int bid = blockIdx.x, tid = threadIdx.x;
  __shared__ float e_lds[64];
  __shared__ float red[512];
  if (bid < 96) {
    const int wave = tid >> 6, lane = tid & 63;
    const int r16 = lane & 15, g = lane >> 4;
    const int sub = wave & 1, kh = wave >> 1;
    const int n0 = (bid * 2 + sub) * 16;
    f32x4 acc = {};
    #pragma unroll 4
    for (int ks = 0; ks < 16; ++ks) {
      int k = kh * 512 + ks * 32 + g * 8;
      bf16x8 a = *(const bf16x8*)&p.sb[r16 * 1024 + k];
      bf16x8 bb = *(const bf16x8*)&p.WhhT[(size_t)(n0 + r16) * 1024 + k];
      acc = __builtin_amdgcn_mfma_f32_16x16x32_bf16(a, bb, acc, 0, 0, 0);
    }
    if (kh == 1) {
      #pragma unroll
      for (int r = 0; r < 4; ++r) red[sub * 256 + lane * 4 + r] = acc[r];
    }
    __syncthreads();
    if (kh == 0) {
      #pragma unroll
      for (int r = 0; r < 4; ++r) {
        float v = acc[r] + red[sub * 256 + lane * 4 + r];
        int row = 4 * g + r, col = n0 + r16;
        p.gh[row * 3072 + col] = v + p.b_hh[col];
      }
    }
  } else if (bid < 864) {
    const int idx = bid - 96, b = idx / 48, c0 = (idx % 48) * 64;
    softmax64(p.abuf + b * 64, e_lds, tid);
    const int col = c0 + (tid & 63), q = tid >> 6;
    float av = 0.0f;
    #pragma unroll
    for (int u = 0; u < 16; ++u) {
      int ts = q * 16 + u;
      av += e_lds[ts] * b2f(p.Hih[(size_t)(b * 64 + ts) * 3072 + col]);
    }
    red[q * 64 + (tid & 63)] = av;
    __syncthreads();
    if (tid < 64) {
      float v = red[tid] + red[64 + tid] + red[128 + tid] + red[192 + tid];
      p.gi[b * 3072 + c0 + tid] = v + p.b_ih[c0 + tid];
    }
  } else {
    const int idx = bid - 864, b = idx >> 3, d0 = (idx & 7) * 256;
    softmax64(p.abuf + b * 64, e_lds, tid);
    float av = 0.0f;
    #pragma unroll 8
    for (int ts = 0; ts < 64; ++ts)
      av += e_lds[ts] * b2f(p.h_bf[(size_t)(b * 64 + ts) * 2048 + d0 + tid]);
    p.X[(size_t)(t * 16 + b) * 3584 + 1536 + d0 + tid] = f2b(av);
  }
}

// ---------------- launch ----------------
extern "C" void kernel_launch(void* const* d_in, const int* in_sizes, int n_in,
                              void* d_out, int out_size, void* d_ws, size_t ws_size,
                              hipStream_t stream) {
  const float* h     = (const float*)d_in[0];
  const float* W_h   = (const float*)d_in[1];
  const float* b_h   = (const float*)d_in[2];
  const float* W_s   = (const float*)d_in[3];
  const float* b_s   = (const float*)d_in[4];
  const float* W_ih  = (const float*)d_in[5];
  const float* b_ih  = (const float*)d_in[6];
  const float* W_hh  = (const float*)d_in[7];
  const float* b_hh  = (const float*)d_in[8];
  const float* W_emb = (const float*)d_in[9];
  const float* b_emb = (const float*)d_in[10];
  const float* W_t   = (const float*)d_in[11];
  const float* b_t   = (const float*)d_in[12];
  const float* W_out = (const float*)d_in[13];
  const float* b_out = (const float*)d_in[14];

  char* base = (char*)d_ws; size_t off = 0;
  auto alloc = [&](size_t bytes) -> void* {
    off = (off + 255) & ~(size_t)255;
    void* pp = base + off; off += bytes; return pp;
  };
  uint16_t* h_bf  = (uint16_t*)alloc((size_t)1024 * 2048 * 2);
  uint16_t* WhT   = (uint16_t*)alloc((size_t)64 * 2048 * 2);
  uint16_t* WsT   = (uint16_t*)alloc((size_t)64 * 1024 * 2);
  uint16_t* WhhT  = (uint16_t*)alloc((size_t)3072 * 1024 * 2);
  uint16_t* WihT  = (uint16_t*)alloc((size_t)3072 * 2048 * 2);
  uint16_t* WembT = (uint16_t*)alloc((size_t)512 * 1024 * 2);
  uint16_t* WtT   = (uint16_t*)alloc((size_t)2048 * 3584 * 2);
  uint16_t* WoutT = (uint16_t*)alloc((size_t)32000 * 1024 * 2);
  float*    hemb  = (float*)alloc((size_t)1024 * 64 * 4);
  uint16_t* Hih   = (uint16_t*)alloc((size_t)1024 * 3072 * 2);
  uint16_t* X     = (uint16_t*)alloc((size_t)1024 * 3584 * 2);
  float*    tt    = (float*)alloc((size_t)1024 * 2048 * 4);
  uint16_t* t_all = (uint16_t*)alloc((size_t)1024 * 1024 * 2);
  float*    abuf  = (float*)alloc((size_t)16 * 64 * 4);
  float*    gi    = (float*)alloc((size_t)16 * 3072 * 4);
  float*    gh    = (float*)alloc((size_t)16 * 3072 * 4);
  float*    sf0   = (float*)alloc((size_t)16 * 1024 * 4);
  float*    sf1   = (float*)alloc((size_t)16 * 1024 * 4);
  uint16_t* sb    = (uint16_t*)alloc((size_t)16 * 1024 * 2);

  // conversions / transposes (all dims multiples of 32)
  k_cvt_bf16<<<2048, 256, 0, stream>>>(h, h_bf, 1024 * 2048 / 4);
  k_transpose_bf16<<<dim3(2, 64), 256, 0, stream>>>(W_h, WhT, 2048, 64);
  k_transpose_bf16<<<dim3(2, 32), 256, 0, stream>>>(W_s, WsT, 1024, 64);
  k_transpose_bf16<<<dim3(96, 32), 256, 0, stream>>>(W_hh, WhhT, 1024, 3072);
  k_transpose_bf16<<<dim3(96, 64), 256, 0, stream>>>(W_ih, WihT, 2048, 3072);
  k_transpose_bf16<<<dim3(16, 32), 256, 0, stream>>>(W_emb, WembT, 1024, 512);
  k_transpose_bf16<<<dim3(64, 112), 256, 0, stream>>>(W_t, WtT, 3584, 2048);
  k_transpose_bf16<<<dim3(1000, 32), 256, 0, stream>>>(W_out, WoutT, 1024, 32000);

  // precompute h_emb = h@W_h + b_h (f32 out) and H_ih = h@W_ih (bf16 out)
  k_gemm<0><<<dim3(1, 8), 256, 0, stream>>>(h_bf, 2048, WhT, 2048, hemb, 64, b_h, 1024, 64, 2048);
  k_gemm<1><<<dim3(24, 8), 256, 0, stream>>>(h_bf, 2048, WihT, 2048, Hih, 3072, nullptr, 1024, 3072, 2048);

  // sequential scan: per-step kernel launches (kernel-boundary sync)
  ScanParams sp{h_bf, WsT, WhhT, Hih, hemb, b_s, b_ih, b_hh, abuf, gi, gh, sf0, sf1, sb, X};
  for (int t = 0; t < 64; ++t) {
    k_stepA<<<64, 256, 0, stream>>>(sp, t);
    k_stepB<<<992, 256, 0, stream>>>(sp, t);
  }
  k_stepFinal<<<16, 256, 0, stream>>>(sp);

  // batched tail: y_emb -> X[:,1024:1536]; t_tilde; maxout; vocab GEMM (remapped store)
  k_gemm<1><<<dim3(4, 8), 256, 0, stream>>>(X, 3584, WembT, 1024, X + 1024, 3584, b_emb, 1024, 512, 1024);
  k_gemm<0><<<dim3(16, 8), 256, 0, stream>>>(X, 3584, WtT, 3584, tt, 2048, b_t, 1024, 2048, 3584);
  k_maxout<<<4096, 256, 0, stream>>>(tt, t_all);
  k_gemm<2><<<dim3(250, 8), 256, 0, stream>>>(t_all, 1024, WoutT, 1024, (float*)d_out, 32000, b_out, 1024, 32000, 1024);
}